// Round 9
// baseline (213.821 us; speedup 1.0000x reference)
//
#include <hip/hip_runtime.h>
#include <math.h>

#define HDIM 64
#define NB1MAX 256          // coarse buckets (512 vars each); V<=131072
#define CAPB 52             // per (block, coarse-bucket) cell capacity (lambda~21, +6.7 sigma)
#define CAP2 7424           // per coarse-bucket record capacity (lambda~6377, +13 sigma)
#define GMAX 1536           // per 64-var group capacity in consumer (lambda~800)
#define NCHMAX 320          // max coarse-partition blocks (E<=1.31M)
#define PK17 0x1FFFF        // src mask; requires src < 2^17 (N_CON=100k ok)

// ---------------------------------------------------------------------------
// P1: coarse partition. 4096 edges/block -> LDS histogram over <=196 coarse
// buckets -> block scan -> LDS-ordered staging -> RUN-COALESCED writes (~21
// contiguous records per cell) into private (block,bucket) cells. Zero global
// atomics, zero memset. This kills the per-lane 4B scatter (64 lines/wave)
// that round 3-8 evidence tags as the invariant ~100 us cost.
// ---------------------------------------------------------------------------
__global__ __launch_bounds__(256) void k_part1(
        const int* __restrict__ src, const int* __restrict__ dst,
        int* __restrict__ cells, int* __restrict__ cmat, int E, int NB1) {
    __shared__ int hist[256], exs[256], cur[256], sc[256];
    __shared__ int stage[4096];              // 16 KB
    __shared__ unsigned char bkt[4096];      // 4 KB
    int t = threadIdx.x;
    int e0 = blockIdx.x << 12;
    int nE = E - e0; if (nE > 4096) nE = 4096; if (nE < 0) nE = 0;

    hist[t] = 0; cur[t] = 0;
    __syncthreads();

    int pk[16], cb[16];                      // edges live in VGPRs (one global read)
    #pragma unroll
    for (int k = 0; k < 16; ++k) {
        int e = e0 + (k << 8) + t;
        pk[k] = -1; cb[k] = 0;
        if (e < E) {
            int d = dst[e];
            cb[k] = d >> 9;
            pk[k] = ((d & 511) << 17) | src[e];   // 26 bits, never -1
            atomicAdd(&hist[cb[k]], 1);
        }
    }
    __syncthreads();
    int h = hist[t];
    sc[t] = h;
    __syncthreads();
    for (int off = 1; off < 256; off <<= 1) {     // Hillis-Steele over 256
        int val = (t >= off) ? sc[t - off] : 0;
        __syncthreads();
        sc[t] += val;
        __syncthreads();
    }
    exs[t] = sc[t] - h;
    if (t < NB1) {
        int hh = h; if (hh > CAPB) hh = CAPB;
        cmat[blockIdx.x * NB1 + t] = hh;          // coalesced
    }
    __syncthreads();
    #pragma unroll
    for (int k = 0; k < 16; ++k) {
        if (pk[k] != -1) {
            int bb = cb[k];
            int r = atomicAdd(&cur[bb], 1);       // LDS returning atomic: rank
            int slot = exs[bb] + r;
            stage[slot] = pk[k];
            bkt[slot] = (unsigned char)bb;
        }
    }
    __syncthreads();
    #pragma unroll
    for (int k = 0; k < 16; ++k) {                // bucket-ordered -> run-coalesced
        int slot = (k << 8) + t;
        if (slot < nE) {
            int bb = bkt[slot];
            int r = slot - exs[bb];
            if (r < CAPB)                         // overflow guard (never in practice)
                cells[((size_t)blockIdx.x * NB1 + bb) * CAPB + r] = stage[slot];
        }
    }
}

// ---------------------------------------------------------------------------
// P2: one block per coarse bucket. Gather its ~306 cells into LDS, exact
// counting sort over 512 vars IN LDS, then write the sorted record stream
// COALESCED plus per-var (offset, degree) tables. All global writes coalesced.
// ---------------------------------------------------------------------------
__global__ __launch_bounds__(256) void k_part2(
        const int* __restrict__ cells, const int* __restrict__ cmat,
        int* __restrict__ recs, int* __restrict__ gvoff, int* __restrict__ gdeg,
        int NCH, int NB1) {
    __shared__ int ccnt[NCHMAX], coff[NCHMAX];
    __shared__ int vcnt[512], vcur[512], voffL[512], sc[256];
    __shared__ int pbuf[CAP2];               // 29 KB
    __shared__ int sbuf[CAP2];               // 29 KB
    __shared__ int totS;
    int t = threadIdx.x, cb = blockIdx.x;
    int wv = t >> 6, lane = t & 63;

    for (int k = t; k < NCHMAX; k += 256) ccnt[k] = 0;
    vcnt[t] = 0; vcnt[t + 256] = 0;
    __syncthreads();
    for (int k = t; k < NCH; k += 256) ccnt[k] = cmat[k * NB1 + cb];
    __syncthreads();
    if (t < 64) {                            // wave 0: scan NCHMAX cell counts
        int running = 0;
        for (int k0 = 0; k0 < NCHMAX; k0 += 64) {
            int v = ccnt[k0 + lane];
            int incl = v;
            #pragma unroll
            for (int off = 1; off < 64; off <<= 1) {
                int u = __shfl_up(incl, off, 64);
                if (lane >= off) incl += u;
            }
            coff[k0 + lane] = running + (incl - v);
            running += __shfl(incl, 63, 64);
        }
        if (lane == 0) totS = running;
    }
    __syncthreads();
    int cnt = totS; if (cnt > CAP2) cnt = CAP2;

    for (int k = wv; k < NCH; k += 4) {      // gather cells (runs of ~21, coalesced)
        int c = ccnt[k];
        if (lane < c) {
            int pk = cells[((size_t)k * NB1 + cb) * CAPB + lane];
            int o = coff[k] + lane;
            if (o < CAP2) {
                pbuf[o] = pk;
                atomicAdd(&vcnt[((unsigned)pk) >> 17], 1);
            }
        }
    }
    __syncthreads();
    int a0 = vcnt[2 * t], a1 = vcnt[2 * t + 1];   // scan 512 var counts
    int s = a0 + a1;
    sc[t] = s;
    __syncthreads();
    for (int off = 1; off < 256; off <<= 1) {
        int val = (t >= off) ? sc[t - off] : 0;
        __syncthreads();
        sc[t] += val;
        __syncthreads();
    }
    int ex = sc[t] - s;
    voffL[2 * t] = ex;      voffL[2 * t + 1] = ex + a0;
    vcur[2 * t]  = ex;      vcur[2 * t + 1]  = ex + a0;
    gvoff[cb * 512 + 2 * t]     = ex;             // coalesced global tables
    gvoff[cb * 512 + 2 * t + 1] = ex + a0;
    gdeg[cb * 512 + 2 * t]      = a0;
    gdeg[cb * 512 + 2 * t + 1]  = a1;
    __syncthreads();
    for (int e = t; e < cnt; e += 256) {     // counting-sort scatter (LDS only)
        int pk = pbuf[e];
        int slot = atomicAdd(&vcur[((unsigned)pk) >> 17], 1);
        sbuf[slot] = pk & PK17;              // keep src only
    }
    __syncthreads();
    for (int e = t; e < cnt; e += 256)       // fully coalesced global write
        recs[(size_t)cb * CAP2 + e] = sbuf[e];
}

// ---------------------------------------------------------------------------
// Consumer: records arrive PRE-SORTED with per-var offset/degree tables —
// no LDS sort needed (removes 2 LDS atomics/edge + 3 barriers; LDS 13->6.5 KB).
// Validated round-6 gather (quarter-wave float4, 2 vars in flight) + W-in-VGPR
// matvec + butterfly transpose-reduce + LayerNorm.
// ---------------------------------------------------------------------------
__global__ __launch_bounds__(256, 4) void k_fused(
        const float* __restrict__ x, const int* __restrict__ recs,
        const int* __restrict__ gvoff, const int* __restrict__ gdeg,
        const float* __restrict__ W, const float* __restrict__ b,
        const float* __restrict__ gamma, const float* __restrict__ beta,
        float* __restrict__ out, int V) {
    __shared__ int sidx[GMAX];
    __shared__ int voffL[64], vcntL[64];
    __shared__ int s0S, ngS;
    int t = threadIdx.x;
    int j = blockIdx.x;                      // 64-var group
    int cb = j >> 3, sub = j & 7;

    if (t < 64) {
        int vo = gvoff[cb * 512 + (sub << 6) + t];
        int dc = gdeg[cb * 512 + (sub << 6) + t];
        int s0 = __shfl(vo, 0, 64);
        voffL[t] = vo - s0;
        vcntL[t] = dc;
        int last = __shfl(vo + dc, 63, 64);
        if (t == 0) { s0S = s0; ngS = last - s0; }
    }
    __syncthreads();
    int n = ngS; if (n > GMAX) n = GMAX;
    {
        const int* rbase = recs + (size_t)cb * CAP2 + s0S;
        for (int e = t; e < n; e += 256) sidx[e] = rbase[e];   // coalesced
    }
    __syncthreads();

    int wv = t >> 6, lane = t & 63, q = lane >> 4, c = lane & 15;
    float4 wreg[16];                         // W[16q+i][4c..4c+3]
    #pragma unroll
    for (int i = 0; i < 16; ++i)
        wreg[i] = *(const float4*)(W + ((((q << 4) + i) << 6)) + (c << 2));
    float b_l = b[lane], g_l = gamma[lane], bt_l = beta[lane];

    for (int jj = 0; jj < 8; ++jj) {
        int vl0 = (wv << 4) + (jj << 1);
        int vl1 = vl0 + 1;
        int v0 = j * 64 + vl0;
        int start0 = voffL[vl0], dg0 = vcntL[vl0];
        int start1 = voffL[vl1], dg1 = vcntL[vl1];

        float a0x = 0, a0y = 0, a0z = 0, a0w = 0;
        float a1x = 0, a1y = 0, a1z = 0, a1w = 0;
        int n2 = dg0 > dg1 ? dg0 : dg1;
        for (int t0 = 0; t0 < n2; t0 += 16) {
            #pragma unroll
            for (int k = 0; k < 4; ++k) {
                int ii = t0 + (k << 2) + q;
                if (ii < dg0) {
                    int sdx = sidx[start0 + ii];        // 16-lane-uniform broadcast
                    const float4 xv = *(const float4*)(x + ((size_t)sdx << 6) + (c << 2));
                    a0x += xv.x; a0y += xv.y; a0z += xv.z; a0w += xv.w;
                }
                if (ii < dg1) {
                    int sdx = sidx[start1 + ii];
                    const float4 xv = *(const float4*)(x + ((size_t)sdx << 6) + (c << 2));
                    a1x += xv.x; a1y += xv.y; a1z += xv.z; a1w += xv.w;
                }
            }
        }
        a0x += __shfl_xor(a0x, 16, 64); a1x += __shfl_xor(a1x, 16, 64);
        a0y += __shfl_xor(a0y, 16, 64); a1y += __shfl_xor(a1y, 16, 64);
        a0z += __shfl_xor(a0z, 16, 64); a1z += __shfl_xor(a1z, 16, 64);
        a0w += __shfl_xor(a0w, 16, 64); a1w += __shfl_xor(a1w, 16, 64);
        a0x += __shfl_xor(a0x, 32, 64); a1x += __shfl_xor(a1x, 32, 64);
        a0y += __shfl_xor(a0y, 32, 64); a1y += __shfl_xor(a1y, 32, 64);
        a0z += __shfl_xor(a0z, 32, 64); a1z += __shfl_xor(a1z, 32, 64);
        a0w += __shfl_xor(a0w, 32, 64); a1w += __shfl_xor(a1w, 32, 64);

        float p0[16], p1[16];
        #pragma unroll
        for (int i = 0; i < 16; ++i) {
            p0[i] = fmaf(wreg[i].x, a0x, fmaf(wreg[i].y, a0y,
                    fmaf(wreg[i].z, a0z, wreg[i].w * a0w)));
            p1[i] = fmaf(wreg[i].x, a1x, fmaf(wreg[i].y, a1y,
                    fmaf(wreg[i].z, a1z, wreg[i].w * a1w)));
        }
        {
            int hi = c & 8;
            #pragma unroll
            for (int k = 0; k < 8; ++k) {
                float k0 = hi ? p0[k + 8] : p0[k], g0 = hi ? p0[k] : p0[k + 8];
                float k1 = hi ? p1[k + 8] : p1[k], g1 = hi ? p1[k] : p1[k + 8];
                p0[k] = k0 + __shfl_xor(g0, 8, 64);
                p1[k] = k1 + __shfl_xor(g1, 8, 64);
            }
        }
        {
            int hi = c & 4;
            #pragma unroll
            for (int k = 0; k < 4; ++k) {
                float k0 = hi ? p0[k + 4] : p0[k], g0 = hi ? p0[k] : p0[k + 4];
                float k1 = hi ? p1[k + 4] : p1[k], g1 = hi ? p1[k] : p1[k + 4];
                p0[k] = k0 + __shfl_xor(g0, 4, 64);
                p1[k] = k1 + __shfl_xor(g1, 4, 64);
            }
        }
        {
            int hi = c & 2;
            #pragma unroll
            for (int k = 0; k < 2; ++k) {
                float k0 = hi ? p0[k + 2] : p0[k], g0 = hi ? p0[k] : p0[k + 2];
                float k1 = hi ? p1[k + 2] : p1[k], g1 = hi ? p1[k] : p1[k + 2];
                p0[k] = k0 + __shfl_xor(g0, 2, 64);
                p1[k] = k1 + __shfl_xor(g1, 2, 64);
            }
        }
        {
            int hi = c & 1;
            float k0 = hi ? p0[1] : p0[0], g0 = hi ? p0[0] : p0[1];
            float k1 = hi ? p1[1] : p1[0], g1 = hi ? p1[0] : p1[1];
            p0[0] = k0 + __shfl_xor(g0, 1, 64);
            p1[0] = k1 + __shfl_xor(g1, 1, 64);
        }

        float dv0 = (float)dg0, inv0 = 1.0f / (dv0 + 1e-6f);
        float dv1 = (float)dg1, inv1 = 1.0f / (dv1 + 1e-6f);
        float h0 = fmaxf((p0[0] + b_l * dv0) * inv0, 0.0f);
        float h1 = fmaxf((p1[0] + b_l * dv1) * inv1, 0.0f);

        float s10 = h0, s20 = h0 * h0, s11 = h1, s21 = h1 * h1;
        #pragma unroll
        for (int off = 32; off > 0; off >>= 1) {
            s10 += __shfl_xor(s10, off, 64); s11 += __shfl_xor(s11, off, 64);
            s20 += __shfl_xor(s20, off, 64); s21 += __shfl_xor(s21, off, 64);
        }
        float mu0 = s10 * (1.0f / 64.0f);
        float var0 = fmaxf(s20 * (1.0f / 64.0f) - mu0 * mu0, 0.0f);
        float r0 = rsqrtf(var0 + 1e-5f);
        float mu1 = s11 * (1.0f / 64.0f);
        float var1 = fmaxf(s21 * (1.0f / 64.0f) - mu1 * mu1, 0.0f);
        float r1 = rsqrtf(var1 + 1e-5f);
        if (v0 < V)
            out[((size_t)v0 << 6) + lane] = (h0 - mu0) * r0 * g_l + bt_l;
        if (v0 + 1 < V)
            out[((size_t)(v0 + 1) << 6) + lane] = (h1 - mu1) * r1 * g_l + bt_l;
    }
}

extern "C" void kernel_launch(void* const* d_in, const int* in_sizes, int n_in,
                              void* d_out, int out_size, void* d_ws, size_t ws_size,
                              hipStream_t stream) {
    const float* x_con = (const float*)d_in[0];
    const int*   src   = (const int*)d_in[1];
    const int*   dst   = (const int*)d_in[2];
    const float* W     = (const float*)d_in[4];
    const float* b     = (const float*)d_in[5];
    const float* gamma = (const float*)d_in[6];
    const float* beta  = (const float*)d_in[7];
    float* out = (float*)d_out;

    int E = in_sizes[1];
    int V = out_size / HDIM;

    int NB1 = (V + 511) >> 9;                // 196 coarse buckets of 512 vars
    int NCH = (E + 4095) >> 12;              // 306 partition blocks (<= NCHMAX)
    int NG  = (V + 63) >> 6;                 // 1563 consumer groups

    // ws: [cells: NCH*NB1*CAPB = 12.5MB][cmat: NCH*NB1][recs: NB1*CAP2 = 5.8MB]
    //     [gvoff: NB1*512][gdeg: NB1*512]   total ~19.3 MB
    int* cells = (int*)d_ws;
    int* cmat  = cells + (size_t)NCH * NB1 * CAPB;
    int* recs  = cmat + (size_t)NCH * NB1;
    int* gvoff = recs + (size_t)NB1 * CAP2;
    int* gdeg  = gvoff + (size_t)NB1 * 512;

    k_part1<<<NCH, 256, 0, stream>>>(src, dst, cells, cmat, E, NB1);
    k_part2<<<NB1, 256, 0, stream>>>(cells, cmat, recs, gvoff, gdeg, NCH, NB1);
    k_fused<<<NG, 256, 0, stream>>>(x_con, recs, gvoff, gdeg, W, b, gamma, beta, out, V);
}

// Round 10
// 199.978 us; speedup vs baseline: 1.0692x; 1.0692x over previous
//
#include <hip/hip_runtime.h>
#include <math.h>

#define HDIM 64
#define VPB 64              // vars per bucket (bucket = dst >> 6)
#define NBR 1600            // LDS array sizing (>= NB = 1563)
#define MAXCAP 1536         // max edges per bucket (mean 800, guard at +23 sigma)
#define PKSHIFT 25          // pk = (vl << 25) | src ; requires src < 2^25
#define PKMASK 0x1FFFFFF

// ---------------------------------------------------------------------------
// Pass 1: partition, rebuilt for LATENCY TOLERANCE (round-9 lesson: every
// preprocessing variant was bound by exposed latency at ~4 waves/CU, not by
// atomics or scatter — both were individually exonerated in r7/r9).
// Same 306-block grid as round 6, but 1024 threads/block -> ~19 waves/CU and
// a quartered critical path (4 edges/thread, 2 barriers total).
// Body: LDS histogram -> one returning global atomic per nonzero
// (block,bucket) -> LDS returning atomic for rank -> direct 4B scatter store
// (proven harmless in r9: coalescing writes bought nothing).
// ---------------------------------------------------------------------------
__global__ __launch_bounds__(1024) void k_partition(
        const int* __restrict__ src, const int* __restrict__ dst,
        int* __restrict__ pairs, int* __restrict__ bcur,
        int E, int NB, int CAP) {
    __shared__ int hist[NBR], cur[NBR], gb[NBR];
    int t = threadIdx.x;
    int e0 = blockIdx.x << 12;

    for (int j = t; j < NBR; j += 1024) { hist[j] = 0; cur[j] = 0; }
    __syncthreads();

    int pk[4], bb[4];                        // edges live in VGPRs (one global read)
    #pragma unroll
    for (int k = 0; k < 4; ++k) {
        int e = e0 + (k << 10) + t;
        pk[k] = -1; bb[k] = 0;
        if (e < E) {
            int d = dst[e];
            bb[k] = d >> 6;
            pk[k] = ((d & (VPB - 1)) << PKSHIFT) | src[e];   // bit31 clear -> never -1
            atomicAdd(&hist[bb[k]], 1);
        }
    }
    __syncthreads();

    for (int j = t; j < NB; j += 1024) {     // ~1.5 iters: aggregated allocation
        int h = hist[j];
        if (h) gb[j] = j * CAP + atomicAdd(&bcur[j << 4], h);
    }
    __syncthreads();

    #pragma unroll
    for (int k = 0; k < 4; ++k) {
        if (pk[k] != -1) {
            int b = bb[k];
            int r = atomicAdd(&cur[b], 1);   // LDS returning atomic: rank in block
            int g = gb[b] + r;
            if (g < (b + 1) * CAP)           // overflow guard (never for real data)
                pairs[g] = pk[k];
        }
    }
}

// ---------------------------------------------------------------------------
// Pass 2 (fused consumer) — VERBATIM round-6 structure (validated ~90 us):
// LDS counting sort (2 LDS atomics/edge) + register gather (quarter-wave
// float4, 2 vars in flight) + W-in-VGPR matvec + butterfly transpose-reduce
// + LayerNorm.
// ---------------------------------------------------------------------------
__global__ __launch_bounds__(256, 4) void k_fused(
        const float* __restrict__ x, const int* __restrict__ pairs,
        const int* __restrict__ bcur, const float* __restrict__ W,
        const float* __restrict__ b, const float* __restrict__ gamma,
        const float* __restrict__ beta, float* __restrict__ out,
        int V, int CAP) {
    __shared__ int pbuf[MAXCAP];
    __shared__ int sidx[MAXCAP];
    __shared__ int vcnt[VPB], vcur[VPB], voff[VPB];
    int t = threadIdx.x;
    int blk = blockIdx.x;
    int base = blk * CAP;
    int cnt = bcur[blk << 4]; if (cnt > CAP) cnt = CAP;

    if (t < VPB) vcnt[t] = 0;
    __syncthreads();
    for (int e = t; e < cnt; e += 256) {
        int pk = pairs[base + e];
        pbuf[e] = pk;
        atomicAdd(&vcnt[((unsigned)pk) >> PKSHIFT], 1);
    }
    __syncthreads();
    if (t < 64) {                            // wave 0: shfl exclusive scan
        int c0 = vcnt[t];
        int pre = c0;
        #pragma unroll
        for (int off = 1; off < 64; off <<= 1) {
            int u = __shfl_up(pre, off, 64);
            if (t >= off) pre += u;
        }
        voff[t] = pre - c0;
        vcur[t] = pre - c0;
    }
    __syncthreads();
    for (int e = t; e < cnt; e += 256) {
        int pk = pbuf[e];
        int slot = atomicAdd(&vcur[((unsigned)pk) >> PKSHIFT], 1);
        sidx[slot] = pk & PKMASK;
    }
    __syncthreads();

    int wv = t >> 6, lane = t & 63, q = lane >> 4, c = lane & 15;
    float4 wreg[16];                         // W[16q+i][4c..4c+3], reused for all vars
    #pragma unroll
    for (int i = 0; i < 16; ++i)
        wreg[i] = *(const float4*)(W + ((((q << 4) + i) << 6)) + (c << 2));
    float b_l = b[lane], g_l = gamma[lane], bt_l = beta[lane];

    for (int j = 0; j < 8; ++j) {
        int vl0 = (wv << 4) + (j << 1);
        int vl1 = vl0 + 1;
        int v0 = blk * VPB + vl0;
        int start0 = voff[vl0], dg0 = vcnt[vl0];
        int start1 = voff[vl1], dg1 = vcnt[vl1];

        float a0x = 0, a0y = 0, a0z = 0, a0w = 0;
        float a1x = 0, a1y = 0, a1z = 0, a1w = 0;
        int n = dg0 > dg1 ? dg0 : dg1;
        for (int t0 = 0; t0 < n; t0 += 16) {
            #pragma unroll
            for (int k = 0; k < 4; ++k) {
                int ii = t0 + (k << 2) + q;
                if (ii < dg0) {
                    int s = sidx[start0 + ii];          // 16-lane-uniform broadcast
                    const float4 xv = *(const float4*)(x + ((size_t)s << 6) + (c << 2));
                    a0x += xv.x; a0y += xv.y; a0z += xv.z; a0w += xv.w;
                }
                if (ii < dg1) {
                    int s = sidx[start1 + ii];
                    const float4 xv = *(const float4*)(x + ((size_t)s << 6) + (c << 2));
                    a1x += xv.x; a1y += xv.y; a1z += xv.z; a1w += xv.w;
                }
            }
        }
        a0x += __shfl_xor(a0x, 16, 64); a1x += __shfl_xor(a1x, 16, 64);
        a0y += __shfl_xor(a0y, 16, 64); a1y += __shfl_xor(a1y, 16, 64);
        a0z += __shfl_xor(a0z, 16, 64); a1z += __shfl_xor(a1z, 16, 64);
        a0w += __shfl_xor(a0w, 16, 64); a1w += __shfl_xor(a1w, 16, 64);
        a0x += __shfl_xor(a0x, 32, 64); a1x += __shfl_xor(a1x, 32, 64);
        a0y += __shfl_xor(a0y, 32, 64); a1y += __shfl_xor(a1y, 32, 64);
        a0z += __shfl_xor(a0z, 32, 64); a1z += __shfl_xor(a1z, 32, 64);
        a0w += __shfl_xor(a0w, 32, 64); a1w += __shfl_xor(a1w, 32, 64);

        float p0[16], p1[16];
        #pragma unroll
        for (int i = 0; i < 16; ++i) {
            p0[i] = fmaf(wreg[i].x, a0x, fmaf(wreg[i].y, a0y,
                    fmaf(wreg[i].z, a0z, wreg[i].w * a0w)));
            p1[i] = fmaf(wreg[i].x, a1x, fmaf(wreg[i].y, a1y,
                    fmaf(wreg[i].z, a1z, wreg[i].w * a1w)));
        }
        {
            int hi = c & 8;
            #pragma unroll
            for (int k = 0; k < 8; ++k) {
                float k0 = hi ? p0[k + 8] : p0[k], g0 = hi ? p0[k] : p0[k + 8];
                float k1 = hi ? p1[k + 8] : p1[k], g1 = hi ? p1[k] : p1[k + 8];
                p0[k] = k0 + __shfl_xor(g0, 8, 64);
                p1[k] = k1 + __shfl_xor(g1, 8, 64);
            }
        }
        {
            int hi = c & 4;
            #pragma unroll
            for (int k = 0; k < 4; ++k) {
                float k0 = hi ? p0[k + 4] : p0[k], g0 = hi ? p0[k] : p0[k + 4];
                float k1 = hi ? p1[k + 4] : p1[k], g1 = hi ? p1[k] : p1[k + 4];
                p0[k] = k0 + __shfl_xor(g0, 4, 64);
                p1[k] = k1 + __shfl_xor(g1, 4, 64);
            }
        }
        {
            int hi = c & 2;
            #pragma unroll
            for (int k = 0; k < 2; ++k) {
                float k0 = hi ? p0[k + 2] : p0[k], g0 = hi ? p0[k] : p0[k + 2];
                float k1 = hi ? p1[k + 2] : p1[k], g1 = hi ? p1[k] : p1[k + 2];
                p0[k] = k0 + __shfl_xor(g0, 2, 64);
                p1[k] = k1 + __shfl_xor(g1, 2, 64);
            }
        }
        {
            int hi = c & 1;
            float k0 = hi ? p0[1] : p0[0], g0 = hi ? p0[0] : p0[1];
            float k1 = hi ? p1[1] : p1[0], g1 = hi ? p1[0] : p1[1];
            p0[0] = k0 + __shfl_xor(g0, 1, 64);
            p1[0] = k1 + __shfl_xor(g1, 1, 64);
        }

        float dv0 = (float)dg0, inv0 = 1.0f / (dv0 + 1e-6f);
        float dv1 = (float)dg1, inv1 = 1.0f / (dv1 + 1e-6f);
        float h0 = fmaxf((p0[0] + b_l * dv0) * inv0, 0.0f);
        float h1 = fmaxf((p1[0] + b_l * dv1) * inv1, 0.0f);

        float s10 = h0, s20 = h0 * h0, s11 = h1, s21 = h1 * h1;
        #pragma unroll
        for (int off = 32; off > 0; off >>= 1) {
            s10 += __shfl_xor(s10, off, 64); s11 += __shfl_xor(s11, off, 64);
            s20 += __shfl_xor(s20, off, 64); s21 += __shfl_xor(s21, off, 64);
        }
        float mu0 = s10 * (1.0f / 64.0f);
        float var0 = fmaxf(s20 * (1.0f / 64.0f) - mu0 * mu0, 0.0f);
        float r0 = rsqrtf(var0 + 1e-5f);
        float mu1 = s11 * (1.0f / 64.0f);
        float var1 = fmaxf(s21 * (1.0f / 64.0f) - mu1 * mu1, 0.0f);
        float r1 = rsqrtf(var1 + 1e-5f);
        if (v0 < V)
            out[((size_t)v0 << 6) + lane] = (h0 - mu0) * r0 * g_l + bt_l;
        if (v0 + 1 < V)
            out[((size_t)(v0 + 1) << 6) + lane] = (h1 - mu1) * r1 * g_l + bt_l;
    }
}

extern "C" void kernel_launch(void* const* d_in, const int* in_sizes, int n_in,
                              void* d_out, int out_size, void* d_ws, size_t ws_size,
                              hipStream_t stream) {
    const float* x_con = (const float*)d_in[0];
    const int*   src   = (const int*)d_in[1];
    const int*   dst   = (const int*)d_in[2];
    const float* W     = (const float*)d_in[4];
    const float* b     = (const float*)d_in[5];
    const float* gamma = (const float*)d_in[6];
    const float* beta  = (const float*)d_in[7];
    float* out = (float*)d_out;

    int E = in_sizes[1];
    int V = out_size / HDIM;

    int NB = (V + VPB - 1) / VPB;            // 1563 buckets of 64 vars
    int avg = (E + NB - 1) / NB;             // ~800 edges/bucket
    int CAP = avg + (avg >> 1) + 256;        // +~23 sigma headroom
    CAP = (CAP + 15) & ~15;
    if (CAP > MAXCAP) CAP = MAXCAP;

    // ws layout: [pairs: NB*CAP int][bcur: NB*16 int padded]
    int* pairs = (int*)d_ws;
    int* bcur  = pairs + (size_t)NB * CAP;

    hipMemsetAsync(bcur, 0, (size_t)NB * 16 * sizeof(int), stream);
    k_partition<<<(E + 4095) / 4096, 1024, 0, stream>>>(src, dst, pairs, bcur, E, NB, CAP);
    k_fused<<<NB, 256, 0, stream>>>(x_con, pairs, bcur, W, b, gamma, beta, out, V, CAP);
}

// Round 11
// 173.439 us; speedup vs baseline: 1.2328x; 1.1530x over previous
//
#include <hip/hip_runtime.h>
#include <math.h>

#define HDIM 64
#define VPB 64              // vars per bucket (bucket = dst >> 6)
#define NBR 1600            // partition LDS array sizing (>= NB = 1563)
#define MAXCAP 1072         // max edges per bucket (mean 800, +9.6 sigma)
#define PKSHIFT 25          // pk = (vl << 25) | src ; requires src < 2^25
#define PKMASK 0x1FFFFFF
#define SSTR 36             // sums LDS var stride (dwords): 16B-aligned, <=2-way banks

typedef __attribute__((ext_vector_type(8))) short s8v;   // 8 bf16 (4 VGPRs)
typedef __attribute__((ext_vector_type(4))) float f4v;   // MFMA C/D

__device__ __forceinline__ int pkbf(float lo, float hi) {   // pack 2 f32 -> 2 bf16
    unsigned ul = __float_as_uint(lo) + 0x8000u;
    unsigned uh = __float_as_uint(hi) + 0x8000u;
    return (int)((ul >> 16) | (uh & 0xffff0000u));
}

// ---------------------------------------------------------------------------
// Pass 1 (r10 version, ~5-10 us): 1024-thread blocks for latency tolerance.
// LDS histogram -> one returning global atomic per nonzero (block,bucket) ->
// LDS rank -> 4B scatter store of packed records.
// ---------------------------------------------------------------------------
__global__ __launch_bounds__(1024) void k_partition(
        const int* __restrict__ src, const int* __restrict__ dst,
        int* __restrict__ pairs, int* __restrict__ bcur,
        int E, int NB, int CAP) {
    __shared__ int hist[NBR], cur[NBR], gb[NBR];
    int t = threadIdx.x;
    int e0 = blockIdx.x << 12;

    for (int j = t; j < NBR; j += 1024) { hist[j] = 0; cur[j] = 0; }
    __syncthreads();

    int pk[4], bb[4];
    #pragma unroll
    for (int k = 0; k < 4; ++k) {
        int e = e0 + (k << 10) + t;
        pk[k] = -1; bb[k] = 0;
        if (e < E) {
            int d = dst[e];
            bb[k] = d >> 6;
            pk[k] = ((d & (VPB - 1)) << PKSHIFT) | src[e];
            atomicAdd(&hist[bb[k]], 1);
        }
    }
    __syncthreads();
    for (int j = t; j < NB; j += 1024) {
        int h = hist[j];
        if (h) gb[j] = j * CAP + atomicAdd(&bcur[j << 4], h);
    }
    __syncthreads();
    #pragma unroll
    for (int k = 0; k < 4; ++k) {
        if (pk[k] != -1) {
            int b = bb[k];
            int r = atomicAdd(&cur[b], 1);
            int g = gb[b] + r;
            if (g < (b + 1) * CAP) pairs[g] = pk[k];
        }
    }
}

// ---------------------------------------------------------------------------
// Pass 2: sort (validated) + gather (validated) + NEW MFMA epilogue.
// Phase A: per var-pair, quarter-wave float4 gather -> combine -> pack bf16
//          sums into wave-private LDS (stride SSTR dwords, 16B aligned).
// Phase B: A-frags = W rows (bf16, k-major per m120-verified A layout);
//          B-frags = sums via 2 ds_read_b128; 8 MFMAs -> all 64x16 outputs.
//          C layout (m89-verified): row=4q+reg(+16i), col=var c.
//          LN = 16-wide per-lane sum + 4 shfls for ALL 16 vars. float4 store.
// ---------------------------------------------------------------------------
__global__ __launch_bounds__(256, 4) void k_fused(
        const float* __restrict__ x, const int* __restrict__ pairs,
        const int* __restrict__ bcur, const float* __restrict__ W,
        const float* __restrict__ b, const float* __restrict__ gamma,
        const float* __restrict__ beta, float* __restrict__ out,
        int V, int CAP) {
    __shared__ int pbuf[MAXCAP];
    __shared__ int sidx[MAXCAP];
    __shared__ int vcnt[VPB], vcur[VPB], voff[VPB];
    __shared__ int sums[4 * 16 * SSTR];      // bf16 sums, wave-private regions
    int t = threadIdx.x;
    int blk = blockIdx.x;
    int base = blk * CAP;
    int cnt = bcur[blk << 4]; if (cnt > CAP) cnt = CAP;

    if (t < VPB) vcnt[t] = 0;
    __syncthreads();
    for (int e = t; e < cnt; e += 256) {
        int pk = pairs[base + e];
        pbuf[e] = pk;
        atomicAdd(&vcnt[((unsigned)pk) >> PKSHIFT], 1);
    }
    __syncthreads();
    if (t < 64) {                            // wave 0: shfl exclusive scan
        int c0 = vcnt[t];
        int pre = c0;
        #pragma unroll
        for (int off = 1; off < 64; off <<= 1) {
            int u = __shfl_up(pre, off, 64);
            if (t >= off) pre += u;
        }
        voff[t] = pre - c0;
        vcur[t] = pre - c0;
    }
    __syncthreads();
    for (int e = t; e < cnt; e += 256) {
        int pk = pbuf[e];
        int slot = atomicAdd(&vcur[((unsigned)pk) >> PKSHIFT], 1);
        sidx[slot] = pk & PKMASK;
    }
    __syncthreads();

    int wv = t >> 6, lane = t & 63, q = lane >> 4, c = lane & 15;
    int sbase = wv * (16 * SSTR);

    // -------- Phase A: gather raw sums for this wave's 16 vars --------------
    for (int j = 0; j < 8; ++j) {
        int lv0 = j << 1, lv1 = lv0 + 1;
        int vl0 = (wv << 4) + lv0, vl1 = vl0 + 1;
        int start0 = voff[vl0], dg0 = vcnt[vl0];
        int start1 = voff[vl1], dg1 = vcnt[vl1];

        float a0x = 0, a0y = 0, a0z = 0, a0w = 0;
        float a1x = 0, a1y = 0, a1z = 0, a1w = 0;
        int n = dg0 > dg1 ? dg0 : dg1;
        for (int t0 = 0; t0 < n; t0 += 16) {
            #pragma unroll
            for (int k = 0; k < 4; ++k) {
                int ii = t0 + (k << 2) + q;
                if (ii < dg0) {
                    int s = sidx[start0 + ii];          // 16-lane-uniform broadcast
                    const float4 xv = *(const float4*)(x + ((size_t)s << 6) + (c << 2));
                    a0x += xv.x; a0y += xv.y; a0z += xv.z; a0w += xv.w;
                }
                if (ii < dg1) {
                    int s = sidx[start1 + ii];
                    const float4 xv = *(const float4*)(x + ((size_t)s << 6) + (c << 2));
                    a1x += xv.x; a1y += xv.y; a1z += xv.z; a1w += xv.w;
                }
            }
        }
        a0x += __shfl_xor(a0x, 16, 64); a1x += __shfl_xor(a1x, 16, 64);
        a0y += __shfl_xor(a0y, 16, 64); a1y += __shfl_xor(a1y, 16, 64);
        a0z += __shfl_xor(a0z, 16, 64); a1z += __shfl_xor(a1z, 16, 64);
        a0w += __shfl_xor(a0w, 16, 64); a1w += __shfl_xor(a1w, 16, 64);
        a0x += __shfl_xor(a0x, 32, 64); a1x += __shfl_xor(a1x, 32, 64);
        a0y += __shfl_xor(a0y, 32, 64); a1y += __shfl_xor(a1y, 32, 64);
        a0z += __shfl_xor(a0z, 32, 64); a1z += __shfl_xor(a1z, 32, 64);
        a0w += __shfl_xor(a0w, 32, 64); a1w += __shfl_xor(a1w, 32, 64);

        if (q == 0) {                        // lane c writes cols 4c..4c+3 (bf16)
            int o0 = sbase + lv0 * SSTR + (c << 1);
            sums[o0]     = pkbf(a0x, a0y);
            sums[o0 + 1] = pkbf(a0z, a0w);
            int o1 = sbase + lv1 * SSTR + (c << 1);
            sums[o1]     = pkbf(a1x, a1y);
            sums[o1 + 1] = pkbf(a1z, a1w);
        }
    }
    __builtin_amdgcn_wave_barrier();         // wave-private LDS; DS ops in-order

    // -------- Phase B: 8 MFMAs -> 64 outputs x 16 vars ----------------------
    union { int i4[4]; s8v v; } af[4][2];    // A: W[16i+c][h*32+8q .. +7]
    #pragma unroll
    for (int i = 0; i < 4; ++i)
        #pragma unroll
        for (int hh = 0; hh < 2; ++hh) {
            const float* wp = W + (((i << 4) + c) << 6) + (hh << 5) + (q << 3);
            float4 wa = *(const float4*)wp;
            float4 wb = *(const float4*)(wp + 4);
            af[i][hh].i4[0] = pkbf(wa.x, wa.y);
            af[i][hh].i4[1] = pkbf(wa.z, wa.w);
            af[i][hh].i4[2] = pkbf(wb.x, wb.y);
            af[i][hh].i4[3] = pkbf(wb.z, wb.w);
        }
    int so = sbase + c * SSTR + (q << 2);    // B: sums[var c][8q..8q+7] (+16dw: k hi)
    union { int4 i; s8v v; } bf1, bf2;
    bf1.i = *(const int4*)&sums[so];
    bf2.i = *(const int4*)&sums[so + 16];

    f4v acc[4];
    #pragma unroll
    for (int i = 0; i < 4; ++i) {
        acc[i] = (f4v){0.f, 0.f, 0.f, 0.f};
        acc[i] = __builtin_amdgcn_mfma_f32_16x16x32_bf16(af[i][0].v, bf1.v, acc[i], 0, 0, 0);
        acc[i] = __builtin_amdgcn_mfma_f32_16x16x32_bf16(af[i][1].v, bf2.v, acc[i], 0, 0, 0);
    }

    float dv  = (float)vcnt[(wv << 4) + c];  // degree of var c (this wave)
    float inv = 1.0f / (dv + 1e-6f);
    float tb  = dv * inv;
    float hreg[16];
    float s1 = 0.f, s2 = 0.f;
    #pragma unroll
    for (int i = 0; i < 4; ++i) {            // h = relu((W@sum + deg*b)*inv)
        float4 bv = *(const float4*)(b + (i << 4) + (q << 2));
        float hv;
        hv = fmaxf(fmaf(bv.x, tb, acc[i][0] * inv), 0.f); hreg[(i<<2)+0] = hv; s1 += hv; s2 = fmaf(hv, hv, s2);
        hv = fmaxf(fmaf(bv.y, tb, acc[i][1] * inv), 0.f); hreg[(i<<2)+1] = hv; s1 += hv; s2 = fmaf(hv, hv, s2);
        hv = fmaxf(fmaf(bv.z, tb, acc[i][2] * inv), 0.f); hreg[(i<<2)+2] = hv; s1 += hv; s2 = fmaf(hv, hv, s2);
        hv = fmaxf(fmaf(bv.w, tb, acc[i][3] * inv), 0.f); hreg[(i<<2)+3] = hv; s1 += hv; s2 = fmaf(hv, hv, s2);
    }
    s1 += __shfl_xor(s1, 16, 64); s1 += __shfl_xor(s1, 32, 64);
    s2 += __shfl_xor(s2, 16, 64); s2 += __shfl_xor(s2, 32, 64);
    float mu   = s1 * (1.0f / 64.0f);
    float var  = fmaxf(s2 * (1.0f / 64.0f) - mu * mu, 0.0f);
    float rstd = rsqrtf(var + 1e-5f);
    float c0n  = -mu * rstd;

    int v = blk * VPB + (wv << 4) + c;
    if (v < V) {
        #pragma unroll
        for (int i = 0; i < 4; ++i) {
            float4 gv  = *(const float4*)(gamma + (i << 4) + (q << 2));
            float4 btv = *(const float4*)(beta  + (i << 4) + (q << 2));
            float4 o;
            o.x = fmaf(fmaf(hreg[(i<<2)+0], rstd, c0n), gv.x, btv.x);
            o.y = fmaf(fmaf(hreg[(i<<2)+1], rstd, c0n), gv.y, btv.y);
            o.z = fmaf(fmaf(hreg[(i<<2)+2], rstd, c0n), gv.z, btv.z);
            o.w = fmaf(fmaf(hreg[(i<<2)+3], rstd, c0n), gv.w, btv.w);
            *(float4*)(out + ((size_t)v << 6) + (i << 4) + (q << 2)) = o;
        }
    }
}

extern "C" void kernel_launch(void* const* d_in, const int* in_sizes, int n_in,
                              void* d_out, int out_size, void* d_ws, size_t ws_size,
                              hipStream_t stream) {
    const float* x_con = (const float*)d_in[0];
    const int*   src   = (const int*)d_in[1];
    const int*   dst   = (const int*)d_in[2];
    const float* W     = (const float*)d_in[4];
    const float* b     = (const float*)d_in[5];
    const float* gamma = (const float*)d_in[6];
    const float* beta  = (const float*)d_in[7];
    float* out = (float*)d_out;

    int E = in_sizes[1];
    int V = out_size / HDIM;

    int NB = (V + VPB - 1) / VPB;            // 1563 buckets of 64 vars
    int avg = (E + NB - 1) / NB;             // ~800 edges/bucket
    int CAP = avg + (avg >> 3) + 160;        // +~9.6 sigma headroom
    CAP = (CAP + 15) & ~15;
    if (CAP > MAXCAP) CAP = MAXCAP;

    // ws layout: [pairs: NB*CAP int][bcur: NB*16 int padded]
    int* pairs = (int*)d_ws;
    int* bcur  = pairs + (size_t)NB * CAP;

    hipMemsetAsync(bcur, 0, (size_t)NB * 16 * sizeof(int), stream);
    k_partition<<<(E + 4095) / 4096, 1024, 0, stream>>>(src, dst, pairs, bcur, E, NB, CAP);
    k_fused<<<NB, 256, 0, stream>>>(x_con, pairs, bcur, W, b, gamma, beta, out, V, CAP);
}